// Round 6
// baseline (113.043 us; speedup 1.0000x reference)
//
#include <hip/hip_runtime.h>
#include <math.h>

#define B 1024
#define O 256
#define D 1024
#define ALPHA 0.005f

#define DS  8            // D splits
#define DCH (D / DS)     // 128 d per slice
#define CH  8            // d per chunk
#define NCH (DCH / CH)   // 16 chunks
#define OPT 4            // o's per block (wave-uniform!)
#define OG  (O / OPT)    // 64 o-groups

// Kernel 0: transpose x[B][D] -> xt[D/4][B] (float4) so lane->b reads coalesce.
__global__ __launch_bounds__(256) void transpose_x(const float* __restrict__ x,
                                                   float4* __restrict__ xt)
{
    const int d4 = blockIdx.x;                       // 0..D/4-1
    const int b  = blockIdx.y * 256 + threadIdx.x;   // 0..B-1
    const float* src = x + (size_t)b * D + d4 * 4;
    xt[(size_t)d4 * B + b] = make_float4(src[0], src[1], src[2], src[3]);
}

// Kernel 1: lane -> b row; the block's 4 centroids are WAVE-UNIFORM, so their
// chunk values load via s_load into SGPRs (scalar pipe), x loads are coalesced
// per-lane float4. Hot loop touches only the VALU + 2 VMEM + a few SMEM per chunk.
// 2048 blocks -> 8 blocks/CU -> 32 waves/CU of TLP.
__global__ __launch_bounds__(256) void dist_part(const float4* __restrict__ xt,
                                                 const float*  __restrict__ c,
                                                 float4* __restrict__ s1p,
                                                 float4* __restrict__ s2p)
{
    const int b  = blockIdx.x * 256 + threadIdx.x;   // batch row (per-lane)
    const int og = blockIdx.y;                       // o-group (uniform)
    const int ds = blockIdx.z;                       // d-slice (uniform)
    const int d4base = ds * (DCH / 4);

    const float* cb = c + (size_t)og * OPT * D + ds * DCH;  // 4 rows, stride D

    float s1[OPT], s2[OPT];
    #pragma unroll
    for (int i = 0; i < OPT; ++i) { s1[i] = 0.f; s2[i] = 0.f; }

    float  cA[OPT][CH], cB[OPT][CH];   // uniform -> SGPRs
    float4 xA[2], xB[2];               // per-lane

#define LOADC(BUF, CHIDX)                                                   \
    { _Pragma("unroll")                                                     \
      for (int oi = 0; oi < OPT; ++oi)                                      \
          _Pragma("unroll")                                                 \
          for (int k = 0; k < CH; ++k)                                      \
              BUF[oi][k] = cb[(size_t)oi * D + (CHIDX) * CH + k]; }

#define LOADX(BUF, CHIDX)                                                   \
    { _Pragma("unroll")                                                     \
      for (int j = 0; j < 2; ++j)                                           \
          BUF[j] = xt[(size_t)(d4base + (CHIDX) * 2 + j) * B + b]; }

#define COMP(CBUF, XBUF)                                                    \
    { float xv[CH];                                                         \
      xv[0] = XBUF[0].x; xv[1] = XBUF[0].y; xv[2] = XBUF[0].z; xv[3] = XBUF[0].w; \
      xv[4] = XBUF[1].x; xv[5] = XBUF[1].y; xv[6] = XBUF[1].z; xv[7] = XBUF[1].w; \
      _Pragma("unroll")                                                     \
      for (int oi = 0; oi < OPT; ++oi)                                      \
          _Pragma("unroll")                                                 \
          for (int k = 0; k < CH; ++k) {                                    \
              float dd = xv[k] - CBUF[oi][k];                               \
              s1[oi] += __builtin_fabsf(dd);                                \
              s2[oi] = __builtin_fmaf(dd, dd, s2[oi]);                      \
          } }

    LOADC(cA, 0)
    LOADX(xA, 0)

    for (int ch = 0; ch < NCH; ch += 2) {
        LOADC(cB, ch + 1)
        LOADX(xB, ch + 1)
        COMP(cA, xA)

        const int nch = (ch + 2 < NCH) ? (ch + 2) : (NCH - 1);
        LOADC(cA, nch)
        LOADX(xA, nch)
        COMP(cB, xB)
    }
#undef LOADC
#undef LOADX
#undef COMP

    // coalesced float4 store: [ds][og][b] -> (s1 for oi=0..3)
    const size_t pidx = ((size_t)ds * OG + og) * B + b;
    s1p[pidx] = make_float4(s1[0], s1[1], s1[2], s1[3]);
    s2p[pidx] = make_float4(s2[0], s2[1], s2[2], s2[3]);
}

// Kernel 2: combine D-slices, sqrt + temperature + alpha row-correction.
__global__ __launch_bounds__(256) void combine_kernel(const float* __restrict__ s1p,
                                                      const float* __restrict__ s2p,
                                                      float* __restrict__ out)
{
    const int b  = blockIdx.x;
    const int o  = threadIdx.x;
    const int og = o >> 2, oi = o & 3;

    float a1 = 0.f, a2 = 0.f;
    #pragma unroll
    for (int ds = 0; ds < DS; ++ds) {
        const size_t idx = (((size_t)ds * OG + og) * B + b) * 4 + oi;
        a1 += s1p[idx];
        a2 += s2p[idx];
    }
    const float v = a1 + 0.5f * __builtin_sqrtf(a2);

    float t = v;
    #pragma unroll
    for (int off = 32; off >= 1; off >>= 1)
        t += __shfl_down(t, off, 64);

    __shared__ float ws[4];
    if ((o & 63) == 0) ws[o >> 6] = t;
    __syncthreads();
    const float S = ws[0] + ws[1] + ws[2] + ws[3];

    out[(size_t)b * O + o] = ALPHA * S - (1.0f + ALPHA) * v;
}

extern "C" void kernel_launch(void* const* d_in, const int* in_sizes, int n_in,
                              void* d_out, int out_size, void* d_ws, size_t ws_size,
                              hipStream_t stream) {
    const float* x = (const float*)d_in[0];   // [B, D]
    const float* c = (const float*)d_in[1];   // [O, D]
    float* out = (float*)d_out;               // [B, O]

    float4* s1p = (float4*)d_ws;                              // [DS, OG, B] f4 = 8.4 MB
    float4* s2p = s1p + (size_t)DS * OG * B;                  // 8.4 MB
    float4* xt  = s2p + (size_t)DS * OG * B;                  // [D/4, B] f4 = 4 MB

    transpose_x<<<dim3(D / 4, B / 256), 256, 0, stream>>>(x, xt);

    dim3 grid(B / 256, OG, DS);               // (4, 64, 8) = 2048 blocks
    dist_part<<<grid, 256, 0, stream>>>(xt, c, s1p, s2p);

    combine_kernel<<<B, 256, 0, stream>>>((const float*)s1p, (const float*)s2p, out);
}

// Round 7
// 90.244 us; speedup vs baseline: 1.2526x; 1.2526x over previous
//
#include <hip/hip_runtime.h>
#include <math.h>

#define B 1024
#define O 256
#define D 1024
#define ALPHA 0.005f

#define BPB 4            // b rows per block (wave-uniform x)
#define DS  8            // D splits
#define DCH (D / DS)     // 128 d per slice
#define CH  4            // d per chunk = 1 float4 of c per lane, 4 floats of x per row
#define NCH (DCH / CH)   // 32 chunks

// Kernel 0: transpose c[O][D] -> ct[D/4][O] (float4) for coalesced c loads (1 MB).
__global__ __launch_bounds__(256) void transpose_c(const float* __restrict__ c,
                                                   float4* __restrict__ ct)
{
    const int o  = threadIdx.x;         // 0..255
    const int d4 = blockIdx.x;          // 0..D/4-1
    const float* src = c + (size_t)o * D + d4 * 4;
    ct[(size_t)d4 * O + o] = make_float4(src[0], src[1], src[2], src[3]);
}

// Kernel 1: lane -> centroid o (coalesced c via ct); the block's 4 x-rows are
// wave-uniform and read straight from global (uniform+invariant -> s_load into
// SGPRs; x chunk state is only 32 floats). No LDS. 2048 blocks at ~32 VGPR ->
// 8 blocks/CU -> 8 waves/SIMD of TLP to bury L2 latency under the 96-cyc/chunk
// VALU stream.
__global__ __launch_bounds__(256, 8) void dist_part(const float* __restrict__ x,
                                                    const float4* __restrict__ ct,
                                                    float* __restrict__ s1p,
                                                    float* __restrict__ s2p)
{
    const int o  = threadIdx.x;               // centroid (per-lane)
    const int b0 = blockIdx.x * BPB;          // first b row (uniform)
    const int ds = blockIdx.y;                // d-slice (uniform)
    const int d0 = ds * DCH;

    const float4* cts = ct + (size_t)(d0 / 4) * O + o;   // step O float4 per d4

    const float* xr[BPB];
    #pragma unroll
    for (int bi = 0; bi < BPB; ++bi)
        xr[bi] = x + (size_t)(b0 + bi) * D + d0;

    float s1[BPB], s2[BPB];
    #pragma unroll
    for (int i = 0; i < BPB; ++i) { s1[i] = 0.f; s2[i] = 0.f; }

    float4 cA, cB;                 // per-lane c chunk (1 float4)
    float  xA[BPB][CH], xB[BPB][CH];   // wave-uniform x chunk (SGPRs)

#define LOADC(BUF, CHIDX)  { BUF = cts[(size_t)(CHIDX) * O]; }

#define LOADX(BUF, CHIDX)                                                   \
    { _Pragma("unroll")                                                     \
      for (int bi = 0; bi < BPB; ++bi)                                      \
          _Pragma("unroll")                                                 \
          for (int k = 0; k < CH; ++k)                                      \
              BUF[bi][k] = xr[bi][(CHIDX) * CH + k]; }

#define COMP(CBUF, XBUF)                                                    \
    { float cv[CH] = {CBUF.x, CBUF.y, CBUF.z, CBUF.w};                      \
      _Pragma("unroll")                                                     \
      for (int bi = 0; bi < BPB; ++bi)                                      \
          _Pragma("unroll")                                                 \
          for (int k = 0; k < CH; ++k) {                                    \
              float dd = XBUF[bi][k] - cv[k];                               \
              s1[bi] += __builtin_fabsf(dd);                                \
              s2[bi] = __builtin_fmaf(dd, dd, s2[bi]);                      \
          } }

    LOADC(cA, 0)
    LOADX(xA, 0)

    for (int ch = 0; ch < NCH; ch += 2) {
        LOADC(cB, ch + 1)
        LOADX(xB, ch + 1)
        COMP(cA, xA)

        const int nch = (ch + 2 < NCH) ? (ch + 2) : (NCH - 1);
        LOADC(cA, nch)
        LOADX(xA, nch)
        COMP(cB, xB)
    }
#undef LOADC
#undef LOADX
#undef COMP

    #pragma unroll
    for (int bi = 0; bi < BPB; ++bi) {
        const size_t idx = ((size_t)ds * B + (b0 + bi)) * O + o;   // coalesced in o
        s1p[idx] = s1[bi];
        s2p[idx] = s2[bi];
    }
}

// Kernel 2: combine D-slices, sqrt + temperature + alpha row-correction.
__global__ __launch_bounds__(256) void combine_kernel(const float* __restrict__ s1p,
                                                      const float* __restrict__ s2p,
                                                      float* __restrict__ out)
{
    const int b = blockIdx.x;
    const int o = threadIdx.x;

    float a1 = 0.f, a2 = 0.f;
    #pragma unroll
    for (int ds = 0; ds < DS; ++ds) {
        const size_t idx = ((size_t)ds * B + b) * O + o;
        a1 += s1p[idx];
        a2 += s2p[idx];
    }
    const float v = a1 + 0.5f * __builtin_sqrtf(a2);

    float t = v;
    #pragma unroll
    for (int off = 32; off >= 1; off >>= 1)
        t += __shfl_down(t, off, 64);

    __shared__ float ws[4];
    if ((o & 63) == 0) ws[o >> 6] = t;
    __syncthreads();
    const float S = ws[0] + ws[1] + ws[2] + ws[3];

    out[(size_t)b * O + o] = ALPHA * S - (1.0f + ALPHA) * v;
}

extern "C" void kernel_launch(void* const* d_in, const int* in_sizes, int n_in,
                              void* d_out, int out_size, void* d_ws, size_t ws_size,
                              hipStream_t stream) {
    const float* x = (const float*)d_in[0];   // [B, D]
    const float* c = (const float*)d_in[1];   // [O, D]
    float* out = (float*)d_out;               // [B, O]

    float*  s1p = (float*)d_ws;                          // [DS, B, O] = 8 MB
    float*  s2p = s1p + (size_t)DS * B * O;              // [DS, B, O] = 8 MB
    float4* ct  = (float4*)(s2p + (size_t)DS * B * O);   // [D/4, O]   = 1 MB

    transpose_c<<<D / 4, O, 0, stream>>>(c, ct);

    dim3 grid(B / BPB, DS);                   // (256, 8) = 2048 blocks
    dist_part<<<grid, 256, 0, stream>>>(x, ct, s1p, s2p);

    combine_kernel<<<B, 256, 0, stream>>>(s1p, s2p, out);
}